// Round 3
// baseline (936.384 us; speedup 1.0000x reference)
//
#include <hip/hip_runtime.h>

// CRF log-likelihood via MFMA-batched linear-domain scan.
// K1 (crf_score): unary+binary scores -> d_ws (256 blocks x 256 thr).
// K2 (crf_scan): 16 blocks x 256 thr; each block scans 16 batches.
//   W0/W1: compute waves. D[j][b] = sum_k E^T[j][k] * Q^T[k][b] via
//          mfma_f32_16x16x32_bf16 (A = E^T static in VGPRs, B = Q^T from LDS).
//          D layout: b = lane&15, j = mt*16 + quad*4 + reg  [m89-verified].
//   W2/W3: producer waves computing u_t = exp(in[t]) into a 4-stage LDS ring
//          (2 steps ahead) -> exp and HBM latency off the critical chain.
// Lag-1 renorm c_b = rcp(S0_prev_b); exact scale bookkeeping Dacc -= log2(c).
// Per-batch capture of sum_j q at t = tfin_b = max(slen_b-1, 1).

#define B_   256
#define LL   1024
#define TT   128
#define NBAT 16
#define NBLK (B_ / NBAT)
#define L2E  1.4426950408889634f
#define LN2f 0.6931471805599453f
#define USTRIDE 132   // dwords per u row (128 + 4 pad)
#define QSTRIDE 136   // shorts per q row (128 + 8 pad)

typedef __attribute__((ext_vector_type(8))) short bf16x8;
typedef __attribute__((ext_vector_type(4))) float f32x4;

__device__ __forceinline__ unsigned bfround(float x) {   // RNE bf16 bits in [31:16]
    unsigned u = __float_as_uint(x);
    return u + 0x7fffu + ((u >> 16) & 1u);
}

__global__ void crf_score(const float* __restrict__ inputs,
                          const int*   __restrict__ tags,
                          const int*   __restrict__ slens,
                          const float* __restrict__ trans,
                          float* __restrict__ scorebuf) {
    const int b = blockIdx.x, tid = threadIdx.x;
    const int lane = tid & 63, wid = tid >> 6;
    __shared__ float wsc[4];
    const int slen = slens[b];
    const float* inb  = inputs + (size_t)b * LL * TT;
    const int*   tagb = tags + b * LL;
    float sc = 0.f;
    for (int t = tid; t < slen; t += 256) {
        int tg = tagb[t];
        float v = inb[(size_t)t * TT + tg];
        if (t >= 1) v += trans[tagb[t - 1] * TT + tg];
        sc += v;
    }
    #pragma unroll
    for (int off = 32; off > 0; off >>= 1) sc += __shfl_xor(sc, off, 64);
    if (lane == 0) wsc[wid] = sc;
    __syncthreads();
    if (tid == 0) scorebuf[b] = wsc[0] + wsc[1] + wsc[2] + wsc[3];
}

__launch_bounds__(256, 1)
__global__ void crf_scan(const float* __restrict__ inputs,
                         const int*   __restrict__ slens,
                         const float* __restrict__ trans,
                         const float* __restrict__ scorebuf,
                         float* __restrict__ out) {
    const int tid  = threadIdx.x;
    const int lane = tid & 63;
    const int wid  = __builtin_amdgcn_readfirstlane(tid >> 6);
    const int quad = lane >> 4;
    const int bl   = lane & 15;
    const int bb0  = blockIdx.x * NBAT;

    __shared__ __align__(16) float ubuf[4][NBAT][USTRIDE];
    __shared__ __align__(16) short qb[2][NBAT][QSTRIDE];
    __shared__ float sbuf[2][NBAT];
    __shared__ float fin[8][NBAT];
    __shared__ float dcap[NBAT];

    // per-lane tfin for its batch; block-max tmax
    const int sl = slens[bb0 + bl];
    int tfin = sl - 1; if (tfin < 1) tfin = 1;
    int tmax = tfin;
    #pragma unroll
    for (int off = 1; off < 16; off <<= 1) {
        int o = __shfl_xor(tmax, off, 64);
        tmax = o > tmax ? o : tmax;
    }
    tmax = __builtin_amdgcn_readfirstlane(tmax);

    // producer-side constants
    const int jh = (wid - 2) * 64;           // j-half base (valid for wid>=2)
    const int pb = lane >> 2;                // producer batch
    const int jg = (lane & 3) * 16;          // j-group within half
    const float* psrc = inputs + (size_t)(bb0 + pb) * LL * TT + jh + jg;

    // consumer-side static A-fragments: A[m=j][k=i] = exp(trans[i][j])
    bf16x8 af[4][4];
    if (wid < 2) {
        #pragma unroll
        for (int mt = 0; mt < 4; ++mt) {
            const int jcol = wid * 64 + mt * 16 + bl;
            #pragma unroll
            for (int kc = 0; kc < 4; ++kc) {
                #pragma unroll
                for (int jj = 0; jj < 8; ++jj) {
                    int i = kc * 32 + quad * 8 + jj;
                    float ev = __builtin_amdgcn_exp2f(trans[i * TT + jcol] * L2E);
                    af[mt][kc][jj] = (short)(bfround(ev) >> 16);
                }
            }
        }
    } else {
        // phase A: fill u stages 0..2
        for (int s = 0; s < 3; ++s) {
            #pragma unroll
            for (int k = 0; k < 4; ++k) {
                float4 v = *(const float4*)(psrc + (size_t)s * TT + 4 * k);
                float4 e;
                e.x = __builtin_amdgcn_exp2f(v.x * L2E);
                e.y = __builtin_amdgcn_exp2f(v.y * L2E);
                e.z = __builtin_amdgcn_exp2f(v.z * L2E);
                e.w = __builtin_amdgcn_exp2f(v.w * L2E);
                *(float4*)&ubuf[s][pb][jh + jg + 4 * k] = e;
            }
        }
    }
    __syncthreads();   // ubuf[0..2] ready

    // phase B: consumers init q_0 = u_0 into qb[1], sbuf[0] = 1
    if (wid < 2) {
        #pragma unroll
        for (int mt = 0; mt < 4; ++mt) {
            const int j0 = wid * 64 + mt * 16 + quad * 4;
            float4 u0 = *(const float4*)&ubuf[0][bl][j0];
            uint2 w;
            w.x = __builtin_amdgcn_perm(bfround(u0.y), bfround(u0.x), 0x07060302);
            w.y = __builtin_amdgcn_perm(bfround(u0.w), bfround(u0.z), 0x07060302);
            *(uint2*)&qb[1][bl][j0] = w;
        }
        if (wid == 0 && quad == 0) sbuf[0][bl] = 1.0f;
    }
    __syncthreads();   // qb[1], sbuf[0] ready

    float Dacc = 0.0f;

    for (int t = 1; t <= tmax; ++t) {
        if (wid < 2) {
            const int cur = t & 1, nxt = (t + 1) & 1;
            // front loads
            bf16x8 bfr[4];
            #pragma unroll
            for (int kc = 0; kc < 4; ++kc)
                bfr[kc] = *(const bf16x8*)&qb[cur][bl][kc * 32 + quad * 8];
            float4 uu[4];
            #pragma unroll
            for (int mt = 0; mt < 4; ++mt)
                uu[mt] = *(const float4*)&ubuf[t & 3][bl][wid * 64 + mt * 16 + quad * 4];
            float sprev = sbuf[(t + 1) & 1][bl];          // == (t-1)&1
            float c = __builtin_amdgcn_rcpf(sprev);
            Dacc -= __builtin_amdgcn_logf(c);             // v_log_f32 = log2

            f32x4 acc[4] = {{0.f,0.f,0.f,0.f},{0.f,0.f,0.f,0.f},
                            {0.f,0.f,0.f,0.f},{0.f,0.f,0.f,0.f}};
            #pragma unroll
            for (int kc = 0; kc < 4; ++kc) {
                #pragma unroll
                for (int mt = 0; mt < 4; ++mt)
                    acc[mt] = __builtin_amdgcn_mfma_f32_16x16x32_bf16(
                        af[mt][kc], bfr[kc], acc[mt], 0, 0, 0);
            }

            // epilogue: q = u * (c * s)
            float q[16];
            #pragma unroll
            for (int mt = 0; mt < 4; ++mt) {
                q[4*mt+0] = uu[mt].x * (c * acc[mt][0]);
                q[4*mt+1] = uu[mt].y * (c * acc[mt][1]);
                q[4*mt+2] = uu[mt].z * (c * acc[mt][2]);
                q[4*mt+3] = uu[mt].w * (c * acc[mt][3]);
            }
            if (wid == 0 && quad == 0) sbuf[cur][bl] = acc[0][0];  // S0 (raw, j=0)

            #pragma unroll
            for (int mt = 0; mt < 4; ++mt) {
                const int j0 = wid * 64 + mt * 16 + quad * 4;
                uint2 w;
                w.x = __builtin_amdgcn_perm(bfround(q[4*mt+1]), bfround(q[4*mt+0]), 0x07060302);
                w.y = __builtin_amdgcn_perm(bfround(q[4*mt+3]), bfround(q[4*mt+2]), 0x07060302);
                *(uint2*)&qb[nxt][bl][j0] = w;
            }

            // rare capture at t == tfin_b
            bool cap = (tfin == t);
            if (__any(cap)) {
                if (cap) {
                    float ps = 0.f;
                    #pragma unroll
                    for (int k = 0; k < 16; ++k) ps += q[k];
                    fin[wid * 4 + quad][bl] = ps;
                    if (wid == 0 && quad == 0) dcap[bl] = Dacc;
                }
            }
        } else {
            int tp = t + 2; if (tp > LL - 1) tp = LL - 1;
            const int st = (t + 2) & 3;
            #pragma unroll
            for (int k = 0; k < 4; ++k) {
                float4 v = *(const float4*)(psrc + (size_t)tp * TT + 4 * k);
                float4 e;
                e.x = __builtin_amdgcn_exp2f(v.x * L2E);
                e.y = __builtin_amdgcn_exp2f(v.y * L2E);
                e.z = __builtin_amdgcn_exp2f(v.z * L2E);
                e.w = __builtin_amdgcn_exp2f(v.w * L2E);
                *(float4*)&ubuf[st][pb][jh + jg + 4 * k] = e;
            }
        }
        __syncthreads();
    }

    // final: logZ_b = ln2 * (log2(sum_j q_tfin) + Dacc_tfin)
    if (wid == 0 && lane < 16) {
        float tot = 0.f;
        #pragma unroll
        for (int i = 0; i < 8; ++i) tot += fin[i][lane];
        float logZ = LN2f * (__builtin_amdgcn_logf(tot) + dcap[lane]);
        out[bb0 + lane] = scorebuf[bb0 + lane] - logZ;
    }
}

extern "C" void kernel_launch(void* const* d_in, const int* in_sizes, int n_in,
                              void* d_out, int out_size, void* d_ws, size_t ws_size,
                              hipStream_t stream) {
    const float* inputs = (const float*)d_in[0];
    const int*   tags   = (const int*)d_in[1];
    const int*   slens  = (const int*)d_in[2];
    const float* trans  = (const float*)d_in[3];
    float* out      = (float*)d_out;
    float* scorebuf = (float*)d_ws;

    crf_score<<<B_, 256, 0, stream>>>(inputs, tags, slens, trans, scorebuf);
    crf_scan<<<NBLK, 256, 0, stream>>>(inputs, slens, trans, scorebuf, out);
}

// Round 4
// 610.279 us; speedup vs baseline: 1.5344x; 1.5344x over previous
//
#include <hip/hip_runtime.h>

// CRF log-likelihood via MFMA-batched linear-domain scan, round 4.
// K1 (crf_score): unary+binary scores -> d_ws.
// K2 (crf_scan): 16 blocks x 4 waves; block scans 16 batches; ALL 4 waves
//   compute (wave w owns j-rows w*32..w*32+31 -> 8 MFMAs/step on its SIMD).
//   q_t (bf16) ping-pongs through LDS qb; u_t = in[t] prefetched into a
//   depth-4 REGISTER ring (use at t, issue for t+4) -> HBM latency spans 4
//   steps. Barriers are raw `s_waitcnt lgkmcnt(0); s_barrier` (no vmcnt(0)
//   drain -> prefetch loads stay in flight across barriers).
// Lag-1 renorm c = rcp(S0_prev), exact scale bookkeeping Dacc += log2(S0).
// Layouts (m89-verified, identical to round 3 which passed absmax=0):
//   A[m=j][k=i]: lane m=lane&15, k=(lane>>4)*8+jj (per 32-k chunk)
//   B[k=i][n=b]: lane n=lane&15, k=(lane>>4)*8+jj
//   D: b=lane&15, j = mtile*16 + (lane>>4)*4 + reg

#define B_   256
#define LL   1024
#define TT   128
#define NBAT 16
#define NBLK (B_ / NBAT)
#define L2E  1.4426950408889634f
#define LN2f 0.6931471805599453f
#define QSTRIDE 136   // shorts per q row (128 + 8 pad)

typedef __attribute__((ext_vector_type(8))) short bf16x8;
typedef __attribute__((ext_vector_type(4))) float f32x4;

__device__ __forceinline__ unsigned bfround(float x) {   // RNE bf16 bits in [31:16]
    unsigned u = __float_as_uint(x);
    return u + 0x7fffu + ((u >> 16) & 1u);
}

__device__ __forceinline__ void lds_barrier() {
    asm volatile("s_waitcnt lgkmcnt(0)\n\ts_barrier" ::: "memory");
}

__global__ void crf_score(const float* __restrict__ inputs,
                          const int*   __restrict__ tags,
                          const int*   __restrict__ slens,
                          const float* __restrict__ trans,
                          float* __restrict__ scorebuf) {
    const int b = blockIdx.x, tid = threadIdx.x;
    const int lane = tid & 63, wid = tid >> 6;
    __shared__ float wsc[4];
    const int slen = slens[b];
    const float* inb  = inputs + (size_t)b * LL * TT;
    const int*   tagb = tags + b * LL;
    float sc = 0.f;
    for (int t = tid; t < slen; t += 256) {
        int tg = tagb[t];
        float v = inb[(size_t)t * TT + tg];
        if (t >= 1) v += trans[tagb[t - 1] * TT + tg];
        sc += v;
    }
    #pragma unroll
    for (int off = 32; off > 0; off >>= 1) sc += __shfl_xor(sc, off, 64);
    if (lane == 0) wsc[wid] = sc;
    __syncthreads();
    if (tid == 0) scorebuf[b] = wsc[0] + wsc[1] + wsc[2] + wsc[3];
}

__launch_bounds__(256, 1)
__global__ void crf_scan(const float* __restrict__ inputs,
                         const int*   __restrict__ slens,
                         const float* __restrict__ trans,
                         const float* __restrict__ scorebuf,
                         float* __restrict__ out) {
    const int tid  = threadIdx.x;
    const int lane = tid & 63;
    const int wid  = __builtin_amdgcn_readfirstlane(tid >> 6);
    const int quad = lane >> 4;
    const int bl   = lane & 15;
    const int bb0  = blockIdx.x * NBAT;

    __shared__ __align__(16) short qb[2][NBAT][QSTRIDE];
    __shared__ float sbuf[2][NBAT];
    __shared__ float fin[16][NBAT];
    __shared__ float dcap[NBAT];

    const int sl = slens[bb0 + bl];
    int tfin = sl - 1; if (tfin < 1) tfin = 1;
    int tmax = tfin;
    #pragma unroll
    for (int off = 1; off < 16; off <<= 1) {
        int o = __shfl_xor(tmax, off, 64);
        tmax = o > tmax ? o : tmax;
    }
    tmax = __builtin_amdgcn_readfirstlane(tmax);

    // A fragments: af[mt][kc][jj] = bf16(exp(trans[k][j])),
    // j = wid*32 + mt*16 + bl,  k = kc*32 + quad*8 + jj
    bf16x8 af[2][4];
    #pragma unroll
    for (int mt = 0; mt < 2; ++mt) {
        const int jcol = wid * 32 + mt * 16 + bl;
        #pragma unroll
        for (int kc = 0; kc < 4; ++kc) {
            #pragma unroll
            for (int jj = 0; jj < 8; ++jj) {
                int k = kc * 32 + quad * 8 + jj;
                float ev = __builtin_amdgcn_exp2f(trans[k * TT + jcol] * L2E);
                af[mt][kc][jj] = (short)(bfround(ev) >> 16);
            }
        }
    }

    // per-lane u source: batch bl, columns wid*32 + mt*16 + quad*4 .. +3
    const float* pu = inputs + (size_t)(bb0 + bl) * LL * TT + wid * 32 + quad * 4;

    // init: q0 = bf16(exp(in[0][j])) into qb[1]; sbuf[0] = 1
    #pragma unroll
    for (int mt = 0; mt < 2; ++mt) {
        float4 v = *(const float4*)(pu + mt * 16);
        uint2 w;
        w.x = __builtin_amdgcn_perm(bfround(__builtin_amdgcn_exp2f(v.y * L2E)),
                                    bfround(__builtin_amdgcn_exp2f(v.x * L2E)), 0x07060302);
        w.y = __builtin_amdgcn_perm(bfround(__builtin_amdgcn_exp2f(v.w * L2E)),
                                    bfround(__builtin_amdgcn_exp2f(v.z * L2E)), 0x07060302);
        *(uint2*)&qb[1][bl][wid * 32 + mt * 16 + quad * 4] = w;
    }
    if (wid == 0 && quad == 0) sbuf[0][bl] = 1.0f;

    // register ring: preload u for t = 1..4 (slot = t & 3)
    float4 up[4][2];
    #pragma unroll
    for (int s = 1; s <= 4; ++s) {
        #pragma unroll
        for (int mt = 0; mt < 2; ++mt)
            up[s & 3][mt] = *(const float4*)(pu + (size_t)s * TT + mt * 16);
    }
    lds_barrier();   // qb[1], sbuf[0] visible

    float Dacc = 0.f;

    for (int tb = 1; tb <= tmax; tb += 4) {
        #pragma unroll
        for (int ph = 0; ph < 4; ++ph) {
            const int t    = tb + ph;
            const int cur  = t & 1;
            const int nxt  = cur ^ 1;
            const int slot = t & 3;            // compile-time per ph (tb%4==1)

            // B fragments from LDS (critical path head)
            bf16x8 bfr[4];
            #pragma unroll
            for (int kc = 0; kc < 4; ++kc)
                bfr[kc] = *(const bf16x8*)&qb[cur][bl][kc * 32 + quad * 8];

            float sprev = sbuf[nxt][bl];       // S0_{t-1}  ((t-1)&1 == nxt)
            float c = __builtin_amdgcn_rcpf(sprev);
            Dacc += __builtin_amdgcn_logf(sprev);   // v_log_f32 = log2

            // u_t from register ring; exp off the critical chain
            float ex[2][4];
            #pragma unroll
            for (int mt = 0; mt < 2; ++mt) {
                float4 v = up[slot][mt];
                ex[mt][0] = __builtin_amdgcn_exp2f(v.x * L2E);
                ex[mt][1] = __builtin_amdgcn_exp2f(v.y * L2E);
                ex[mt][2] = __builtin_amdgcn_exp2f(v.z * L2E);
                ex[mt][3] = __builtin_amdgcn_exp2f(v.w * L2E);
            }
            // issue prefetch for t+4 into the freed slot
            {
                int tp = t + 4; if (tp > LL - 1) tp = LL - 1;
                #pragma unroll
                for (int mt = 0; mt < 2; ++mt)
                    up[slot][mt] = *(const float4*)(pu + (size_t)tp * TT + mt * 16);
            }

            // s = E^T q : 8 MFMAs, two independent depth-4 chains
            f32x4 acc[2] = {{0.f,0.f,0.f,0.f},{0.f,0.f,0.f,0.f}};
            #pragma unroll
            for (int kc = 0; kc < 4; ++kc) {
                acc[0] = __builtin_amdgcn_mfma_f32_16x16x32_bf16(af[0][kc], bfr[kc], acc[0], 0, 0, 0);
                acc[1] = __builtin_amdgcn_mfma_f32_16x16x32_bf16(af[1][kc], bfr[kc], acc[1], 0, 0, 0);
            }

            // epilogue: q_t = u_t * (c * s)
            float q[8];
            #pragma unroll
            for (int mt = 0; mt < 2; ++mt) {
                #pragma unroll
                for (int r = 0; r < 4; ++r)
                    q[mt * 4 + r] = ex[mt][r] * (c * acc[mt][r]);
            }
            if (wid == 0 && quad == 0) sbuf[cur][bl] = acc[0][0];   // raw S0_t (j=0)

            #pragma unroll
            for (int mt = 0; mt < 2; ++mt) {
                uint2 w;
                w.x = __builtin_amdgcn_perm(bfround(q[mt*4+1]), bfround(q[mt*4+0]), 0x07060302);
                w.y = __builtin_amdgcn_perm(bfround(q[mt*4+3]), bfround(q[mt*4+2]), 0x07060302);
                *(uint2*)&qb[nxt][bl][wid * 32 + mt * 16 + quad * 4] = w;
            }

            // rare per-batch capture at t == tfin_b
            bool cap = (tfin == t);
            if (__any(cap)) {
                if (cap) {
                    float ps = ((q[0]+q[1])+(q[2]+q[3])) + ((q[4]+q[5])+(q[6]+q[7]));
                    fin[wid * 4 + quad][bl] = ps;
                    if (wid == 0 && quad == 0) dcap[bl] = Dacc;
                }
            }
            lds_barrier();
        }
    }

    // logZ_b = ln2 * (log2(sum_j q_tfin) + Dacc_tfin)
    if (wid == 0 && lane < 16) {
        float tot = 0.f;
        #pragma unroll
        for (int i = 0; i < 16; ++i) tot += fin[i][lane];
        float logZ = LN2f * (__builtin_amdgcn_logf(tot) + dcap[lane]);
        out[bb0 + lane] = scorebuf[bb0 + lane] - logZ;
    }
}

extern "C" void kernel_launch(void* const* d_in, const int* in_sizes, int n_in,
                              void* d_out, int out_size, void* d_ws, size_t ws_size,
                              hipStream_t stream) {
    const float* inputs = (const float*)d_in[0];
    const int*   tags   = (const int*)d_in[1];
    const int*   slens  = (const int*)d_in[2];
    const float* trans  = (const float*)d_in[3];
    float* out      = (float*)d_out;
    float* scorebuf = (float*)d_ws;

    crf_score<<<B_, 256, 0, stream>>>(inputs, tags, slens, trans, scorebuf);
    crf_scan<<<NBLK, 256, 0, stream>>>(inputs, slens, trans, scorebuf, out);
}